// Round 1
// baseline (1853.515 us; speedup 1.0000x reference)
//
#include <hip/hip_runtime.h>
#include <math.h>

// Problem constants (fixed by reference setup_inputs)
#define BHN 16        // B*H
#define NN 16384      // sequence length
#define DD 64         // head dim
#define MM 266        // projection rows

constexpr float DN    = 0.35355339059327373f;   // 64^-0.25
constexpr float HDN2  = 0.0625f;                // 0.5 * DN^2
constexpr float RATIO = 0.0613139339f;          // 266^-0.5
constexpr float EPSF  = 1e-4f;

// ws layout (float offsets)
#define WS_STAB 0                   // [16]
#define WS_PART 16                  // [16][64]
#define WS_KC   1040                // [16][266]
#define WS_CTX  5296                // [16][266][64]
#define WS_FLOATS 277680

// ---------------- Kernel A: per-block max of dd_k ----------------
__global__ __launch_bounds__(256) void kmax_kernel(
    const float* __restrict__ K, const float* __restrict__ P, float* __restrict__ ws)
{
  __shared__ float pl[MM * DD];      // 68 KB, broadcast reads
  __shared__ float red[256];
  const int tid = threadIdx.x;
  const int bh  = blockIdx.x;
  {
    const float4* src = (const float4*)P;
    float4* dst = (float4*)pl;
    for (int i = tid; i < MM * 16; i += 256) dst[i] = src[i];
  }
  __syncthreads();
  const int n = blockIdx.y * 256 + tid;
  const float4* krow = (const float4*)(K + ((size_t)bh * NN + n) * DD);
  float4 kr[16];
#pragma unroll
  for (int i = 0; i < 16; i++) kr[i] = krow[i];
  float mx = -1e30f;
  for (int m = 0; m < MM; m += 2) {          // 266 is even
    const float4* p0 = (const float4*)(pl + m * DD);
    const float4* p1 = (const float4*)(pl + (m + 1) * DD);
    float4 a0 = {0, 0, 0, 0}, a1 = {0, 0, 0, 0};
#pragma unroll
    for (int i = 0; i < 16; i++) {
      float4 q0 = p0[i], q1 = p1[i], k4 = kr[i];
      a0.x += k4.x * q0.x; a0.y += k4.y * q0.y; a0.z += k4.z * q0.z; a0.w += k4.w * q0.w;
      a1.x += k4.x * q1.x; a1.y += k4.y * q1.y; a1.z += k4.z * q1.z; a1.w += k4.w * q1.w;
    }
    float s0 = (a0.x + a0.y) + (a0.z + a0.w);
    float s1 = (a1.x + a1.y) + (a1.z + a1.w);
    mx = fmaxf(mx, fmaxf(s0, s1));
  }
  red[tid] = mx;
  __syncthreads();
  for (int s = 128; s > 0; s >>= 1) {
    if (tid < s) red[tid] = fmaxf(red[tid], red[tid + s]);
    __syncthreads();
  }
  if (tid == 0) ws[WS_PART + bh * 64 + blockIdx.y] = red[0] * DN;  // DN > 0, scale after max
}

// ---------------- Kernel A2: reduce partials -> stab[16] ----------------
__global__ void stab_kernel(float* __restrict__ ws)
{
  const int t = threadIdx.x;
  if (t < BHN) {
    float m = -1e30f;
    for (int i = 0; i < 64; i++) m = fmaxf(m, ws[WS_PART + t * 64 + i]);
    ws[WS_STAB + t] = m;
  }
}

// ---------------- Kernel B: kc + context accumulation ----------------
#define B_TR 128
#define B_MS 32
#define KP_STRIDE 36   // 16B-aligned, breaks power-of-2 write conflicts

__global__ __launch_bounds__(256) void ctx_kernel(
    const float* __restrict__ K, const float* __restrict__ V,
    const float* __restrict__ P, float* __restrict__ ws)
{
  __shared__ float pl[B_MS * DD];            // 8 KB proj slice
  __shared__ float vl[B_TR * DD];            // 32 KB v tile (stride 64: 2-way = free)
  __shared__ float kpl[B_TR * KP_STRIDE];    // 18 KB kp tile
  const int tid = threadIdx.x;
  const int bh  = blockIdx.x;
  const int m0  = blockIdx.y * B_MS;
  const float stab = ws[WS_STAB + bh];
  for (int i = tid; i < B_MS * DD; i += 256) {
    int m = m0 + i / DD;
    pl[i] = (m < MM) ? P[(size_t)m0 * DD + i] : 0.0f;
  }
  __syncthreads();
  const int r   = tid & 127;          // row within tile
  const int mh  = tid >> 7;           // m-half for kp compute
  const int dl  = tid & 63;           // owned d for ctx accum
  const int m8  = (tid >> 6) * 8;     // owned m-group base (wave-uniform)
  float acc[8];
#pragma unroll
  for (int i = 0; i < 8; i++) acc[i] = 0.f;
  float kcacc = 0.f;

  for (int tt = blockIdx.z; tt < NN / B_TR; tt += 7) {
    const int n0 = tt * B_TR;
    // issue v tile loads early (latency)
    float4 vreg[8];
    const float4* vsrc = (const float4*)(V + ((size_t)bh * NN + n0) * DD);
#pragma unroll
    for (int j = 0; j < 8; j++) vreg[j] = vsrc[tid + j * 256];
    // kp for row r, m-half mh
    const float4* krow = (const float4*)(K + ((size_t)bh * NN + n0 + r) * DD);
    float4 kr[16];
#pragma unroll
    for (int i = 0; i < 16; i++) kr[i] = krow[i];
    float sk = 0.f;
#pragma unroll
    for (int i = 0; i < 16; i++)
      sk += kr[i].x * kr[i].x + kr[i].y * kr[i].y + kr[i].z * kr[i].z + kr[i].w * kr[i].w;
    const float dg = HDN2 * sk;
    float kpv[16];
    for (int j = 0; j < 16; j += 2) {
      const int m = mh * 16 + j;
      const float4* p0 = (const float4*)(pl + m * DD);
      const float4* p1 = (const float4*)(pl + (m + 1) * DD);
      float4 a0 = {0, 0, 0, 0}, a1 = {0, 0, 0, 0};
#pragma unroll
      for (int i = 0; i < 16; i++) {
        float4 q0 = p0[i], q1 = p1[i], k4 = kr[i];
        a0.x += k4.x * q0.x; a0.y += k4.y * q0.y; a0.z += k4.z * q0.z; a0.w += k4.w * q0.w;
        a1.x += k4.x * q1.x; a1.y += k4.y * q1.y; a1.z += k4.z * q1.z; a1.w += k4.w * q1.w;
      }
      float s0 = (a0.x + a0.y) + (a0.z + a0.w);
      float s1 = (a1.x + a1.y) + (a1.z + a1.w);
      kpv[j]     = (m0 + m     < MM) ? RATIO * (__expf(DN * s0 - dg - stab) + EPSF) : 0.f;
      kpv[j + 1] = (m0 + m + 1 < MM) ? RATIO * (__expf(DN * s1 - dg - stab) + EPSF) : 0.f;
    }
    __syncthreads();   // previous tile's readers done
    {
      float4* dst = (float4*)vl;
#pragma unroll
      for (int j = 0; j < 8; j++) dst[tid + j * 256] = vreg[j];
    }
#pragma unroll
    for (int j = 0; j < 16; j += 4) {
      float4 w; w.x = kpv[j]; w.y = kpv[j + 1]; w.z = kpv[j + 2]; w.w = kpv[j + 3];
      *(float4*)(kpl + r * KP_STRIDE + mh * 16 + j) = w;
    }
    __syncthreads();   // tile data ready
    if (tid < 32) {    // kc partial (conflict-free: (4r+t)%32 distinct)
#pragma unroll 4
      for (int rr = 0; rr < B_TR; rr++) kcacc += kpl[rr * KP_STRIDE + tid];
    }
#pragma unroll 2
    for (int rr = 0; rr < B_TR; rr++) {
      const float vv = vl[rr * DD + dl];
      const float4 a = *(const float4*)(kpl + rr * KP_STRIDE + m8);      // broadcast
      const float4 b = *(const float4*)(kpl + rr * KP_STRIDE + m8 + 4);  // broadcast
      acc[0] += a.x * vv; acc[1] += a.y * vv; acc[2] += a.z * vv; acc[3] += a.w * vv;
      acc[4] += b.x * vv; acc[5] += b.y * vv; acc[6] += b.z * vv; acc[7] += b.w * vv;
    }
  }
  if (tid < 32) {
    const int m = m0 + tid;
    if (m < MM) atomicAdd(&ws[WS_KC + bh * MM + m], kcacc);
  }
#pragma unroll
  for (int i = 0; i < 8; i++) {
    const int m = m0 + m8 + i;
    if (m < MM) atomicAdd(&ws[WS_CTX + ((size_t)bh * MM + m) * DD + dl], acc[i]);
  }
}

// ---------------- Kernel C: qp + normalize + output ----------------
#define CTX_STRIDE 68   // 16B-aligned pad; col 64 holds kc

__global__ __launch_bounds__(256) void out_kernel(
    const float* __restrict__ Q, const float* __restrict__ P,
    const float* __restrict__ ws, float* __restrict__ Out)
{
  __shared__ float pl[MM * DD];           // 68 KB
  __shared__ float cl[MM * CTX_STRIDE];   // 72.4 KB (context + kc)
  const int tid = threadIdx.x;
  const int bh  = blockIdx.x;
  {
    const float4* src = (const float4*)P;
    float4* dst = (float4*)pl;
    for (int i = tid; i < MM * 16; i += 256) dst[i] = src[i];
    const float4* csrc = (const float4*)(ws + WS_CTX + (size_t)bh * MM * DD);
    float4* cdst = (float4*)cl;
    for (int i = tid; i < MM * 16; i += 256) {
      int m = i >> 4, q = i & 15;
      cdst[m * 17 + q] = csrc[i];
    }
    for (int m = tid; m < MM; m += 256) cl[m * CTX_STRIDE + 64] = ws[WS_KC + bh * MM + m];
  }
  __syncthreads();
  const int n = blockIdx.y * 256 + tid;
  const float4* qrow = (const float4*)(Q + ((size_t)bh * NN + n) * DD);
  float4 qr[16];
#pragma unroll
  for (int i = 0; i < 16; i++) qr[i] = qrow[i];
  float sq = 0.f;
#pragma unroll
  for (int i = 0; i < 16; i++)
    sq += qr[i].x * qr[i].x + qr[i].y * qr[i].y + qr[i].z * qr[i].z + qr[i].w * qr[i].w;
  const float dg = HDN2 * sq;
  // pass 1: row max of raw dot
  float mx = -1e30f;
  for (int m = 0; m < MM; m += 2) {
    const float4* p0 = (const float4*)(pl + m * DD);
    const float4* p1 = (const float4*)(pl + (m + 1) * DD);
    float4 a0 = {0, 0, 0, 0}, a1 = {0, 0, 0, 0};
#pragma unroll
    for (int i = 0; i < 16; i++) {
      float4 q0 = p0[i], q1 = p1[i], k4 = qr[i];
      a0.x += k4.x * q0.x; a0.y += k4.y * q0.y; a0.z += k4.z * q0.z; a0.w += k4.w * q0.w;
      a1.x += k4.x * q1.x; a1.y += k4.y * q1.y; a1.z += k4.z * q1.z; a1.w += k4.w * q1.w;
    }
    float s0 = (a0.x + a0.y) + (a0.z + a0.w);
    float s1 = (a1.x + a1.y) + (a1.z + a1.w);
    mx = fmaxf(mx, fmaxf(s0, s1));
  }
  const float sub = dg + DN * mx;   // diag + stab
  // pass 2: qp -> denom + out accumulation
  float4 oa[16];
#pragma unroll
  for (int i = 0; i < 16; i++) oa[i] = make_float4(0.f, 0.f, 0.f, 0.f);
  float denom = 0.f;
  for (int m = 0; m < MM; m++) {
    const float4* p0 = (const float4*)(pl + m * DD);
    float4 a0 = {0, 0, 0, 0};
#pragma unroll
    for (int i = 0; i < 16; i++) {
      float4 p = p0[i], k4 = qr[i];
      a0.x += k4.x * p.x; a0.y += k4.y * p.y; a0.z += k4.z * p.z; a0.w += k4.w * p.w;
    }
    const float s0 = (a0.x + a0.y) + (a0.z + a0.w);
    const float qp = RATIO * (__expf(DN * s0 - sub) + EPSF);
    denom += qp * cl[m * CTX_STRIDE + 64];
    const float4* c4 = (const float4*)(cl + m * CTX_STRIDE);
#pragma unroll
    for (int i = 0; i < 16; i++) {
      float4 c = c4[i];
      oa[i].x += qp * c.x; oa[i].y += qp * c.y; oa[i].z += qp * c.z; oa[i].w += qp * c.w;
    }
  }
  const float dinv = 1.0f / denom;
  float4* orow = (float4*)(Out + ((size_t)bh * NN + n) * DD);
#pragma unroll
  for (int i = 0; i < 16; i++) {
    float4 o;
    o.x = oa[i].x * dinv; o.y = oa[i].y * dinv; o.z = oa[i].z * dinv; o.w = oa[i].w * dinv;
    orow[i] = o;
  }
}

extern "C" void kernel_launch(void* const* d_in, const int* in_sizes, int n_in,
                              void* d_out, int out_size, void* d_ws, size_t ws_size,
                              hipStream_t stream)
{
  const float* q = (const float*)d_in[0];
  const float* k = (const float*)d_in[1];
  const float* v = (const float*)d_in[2];
  const float* p = (const float*)d_in[3];
  float* out = (float*)d_out;
  float* ws  = (float*)d_ws;

  hipMemsetAsync(d_ws, 0, WS_FLOATS * sizeof(float), stream);

  dim3 gA(BHN, NN / 256);
  kmax_kernel<<<gA, 256, 0, stream>>>(k, p, ws);
  stab_kernel<<<1, 64, 0, stream>>>(ws);
  dim3 gB(BHN, 9, 7);   // 1008 blocks ~ 2 waves of 512 (2 blocks/CU at 58KB LDS)
  ctx_kernel<<<gB, 256, 0, stream>>>(k, v, p, ws);
  dim3 gC(BHN, NN / 256);
  out_kernel<<<gC, 256, 0, stream>>>(q, p, ws, out);
}

// Round 2
// 754.247 us; speedup vs baseline: 2.4574x; 2.4574x over previous
//
#include <hip/hip_runtime.h>
#include <math.h>

// Problem constants: B*H=16, N=16384, D=64, M=266 (padded to 272 = 17 tiles of 16)
#define BHN 16
#define NN 16384
#define DD 64
#define MM 266
#define MP 272          // padded M (17 MFMA tiles)
#define CTS 288         // ctxT row stride (bf16), 16B-aligned chunks

constexpr float DN    = 0.35355339059327373f;   // 64^-0.25
constexpr float HDN2  = 0.0625f;                // 0.5 * DN^2
constexpr float RATIO = 0.0613139339f;          // 266^-0.5
constexpr float EPSF  = 1e-4f;

// ws layout (float offsets)
#define WS_STAB 0                        // [16]
#define WS_PART 16                       // [16][256]
#define WS_KC   4112                     // [16][288] fp32 (pads stay 0)
#define WS_CTX  8720                     // [16][272][64] fp32
#define WS_PBH  287248                   // 272*64 ushort (bf16 hi of proj)
// pbl follows pbh; ctxT hi/lo follow (see kernel_launch)
#define ZERO_OFF 4112
#define ZERO_CNT 283136                  // KC + CTX

typedef __attribute__((ext_vector_type(8))) short s16x8;   // 8 bf16 (4 VGPRs)
typedef __attribute__((ext_vector_type(4))) float f32x4;

#define MFMA(acc, a, b) acc = __builtin_amdgcn_mfma_f32_16x16x32_bf16(a, b, acc, 0, 0, 0)

__device__ __forceinline__ unsigned short f2bf(float f) {
  union { float f; unsigned u; } v; v.f = f;
  unsigned u = v.u;
  return (unsigned short)((u + 0x7fffu + ((u >> 16) & 1u)) >> 16);   // RNE
}
__device__ __forceinline__ float bf2f(unsigned short h) {
  union { unsigned u; float f; } v; v.u = ((unsigned)h) << 16;
  return v.f;
}
// load 8 consecutive fp32, produce bf16 hi/lo fragments + sum-of-squares partial
__device__ __forceinline__ void split8(const float* __restrict__ p,
                                       s16x8& hi, s16x8& lo, float& ss) {
  float4 f0 = *(const float4*)p;
  float4 f1 = *(const float4*)(p + 4);
  float v[8] = {f0.x, f0.y, f0.z, f0.w, f1.x, f1.y, f1.z, f1.w};
#pragma unroll
  for (int i = 0; i < 8; i++) {
    ss += v[i] * v[i];
    unsigned short h = f2bf(v[i]);
    hi[i] = (short)h;
    lo[i] = (short)f2bf(v[i] - bf2f(h));
  }
}

// ---------------- prep: proj -> bf16 hi/lo [272][64], pads zero ----------------
__global__ void prep_kernel(const float* __restrict__ P,
                            unsigned short* __restrict__ pbh,
                            unsigned short* __restrict__ pbl) {
  int idx = blockIdx.x * 256 + threadIdx.x;      // < 272*64
  if (idx < MP * DD) {
    float f = (idx < MM * DD) ? P[idx] : 0.f;    // rows 266..271 zero
    unsigned short h = f2bf(f);
    pbh[idx] = h;
    pbl[idx] = f2bf(f - bf2f(h));
  }
}

// ---------------- kmax: per-block max of raw k.projT ----------------
__global__ __launch_bounds__(256) void kmax_kernel(
    const float* __restrict__ K, const unsigned short* __restrict__ pbh,
    const unsigned short* __restrict__ pbl, float* __restrict__ ws) {
  const int tid = threadIdx.x;
  const int wave = tid >> 6, lane = tid & 63;
  const int l15 = lane & 15, quad = lane >> 4;
  const int bh = blockIdx.x;
  const int n0 = blockIdx.y * 64 + wave * 16;
  s16x8 ah[2], al[2];
  float ss = 0.f;
  const float* kb = K + ((size_t)(bh * NN + n0 + l15)) * DD + quad * 8;
#pragma unroll
  for (int s = 0; s < 2; s++) split8(kb + s * 32, ah[s], al[s], ss);
  float mx = -1e30f;
  for (int t = 0; t < 17; t++) {
    f32x4 dd = {0.f, 0.f, 0.f, 0.f};
#pragma unroll
    for (int s = 0; s < 2; s++) {
      const unsigned short* pb = pbh + (t * 16 + l15) * DD + s * 32 + quad * 8;
      const unsigned short* pl = pbl + (t * 16 + l15) * DD + s * 32 + quad * 8;
      s16x8 b8h = *(const s16x8*)pb;
      s16x8 b8l = *(const s16x8*)pl;
      MFMA(dd, ah[s], b8h); MFMA(dd, al[s], b8h); MFMA(dd, ah[s], b8l);
    }
    if (!(t == 16 && l15 >= 10))   // mask padded m (266..271)
      mx = fmaxf(mx, fmaxf(fmaxf(dd[0], dd[1]), fmaxf(dd[2], dd[3])));
  }
#pragma unroll
  for (int d = 1; d < 64; d <<= 1) mx = fmaxf(mx, __shfl_xor(mx, d));
  __shared__ float red[4];
  if (lane == 0) red[wave] = mx;
  __syncthreads();
  if (tid == 0)
    ws[WS_PART + bh * 256 + blockIdx.y] = fmaxf(fmaxf(red[0], red[1]), fmaxf(red[2], red[3]));
}

// ---------------- stab: reduce partials ----------------
__global__ void stab_kernel(float* __restrict__ ws) {
  __shared__ float red[256];
  const int bh = blockIdx.x, tid = threadIdx.x;
  red[tid] = ws[WS_PART + bh * 256 + tid];
  __syncthreads();
  for (int s = 128; s > 0; s >>= 1) {
    if (tid < s) red[tid] = fmaxf(red[tid], red[tid + s]);
    __syncthreads();
  }
  if (tid == 0) ws[WS_STAB + bh] = DN * red[0];
}

// ---------------- ctx: kp = f(k.projT); ctx += kp^T.v; kc += sum kp ----------------
// grid (16, 32): head x n-split. Each block: 512 rows in 16 chunks of 32.
// Waves own m-tiles t = wave + 4*ti (wave0 gets 5 incl. tile 16).
__global__ __launch_bounds__(256) void ctx_kernel(
    const float* __restrict__ K, const float* __restrict__ V,
    const unsigned short* __restrict__ pbh, const unsigned short* __restrict__ pbl,
    float* __restrict__ ws) {
  __shared__ float vT[64 * 36];      // v chunk transposed [d][n], pad 36
  __shared__ float kpb[MP * 36];     // kp chunk transposed [m][n], pad 36
  const int tid = threadIdx.x;
  const int wave = tid >> 6, lane = tid & 63;
  const int l15 = lane & 15, quad = lane >> 4;
  const int bh = blockIdx.x;
  const float stab = ws[WS_STAB + bh];
  f32x4 zero4 = {0.f, 0.f, 0.f, 0.f};
  f32x4 acc[5][4];
#pragma unroll
  for (int i = 0; i < 5; i++)
#pragma unroll
    for (int j = 0; j < 4; j++) acc[i][j] = zero4;
  float kcp[5] = {0.f, 0.f, 0.f, 0.f, 0.f};

  for (int it = 0; it < 16; it++) {
    const int n0 = blockIdx.y * 512 + it * 32;
    // stage vT (coalesced read, transposed scalar write)
#pragma unroll
    for (int rr = 0; rr < 2; rr++) {
      int idx = rr * 256 + tid;
      int n = idx >> 4, d4 = (idx & 15) * 4;
      float4 vv = *(const float4*)(V + ((size_t)(bh * NN + n0 + n)) * DD + d4);
      vT[(d4 + 0) * 36 + n] = vv.x;
      vT[(d4 + 1) * 36 + n] = vv.y;
      vT[(d4 + 2) * 36 + n] = vv.z;
      vT[(d4 + 3) * 36 + n] = vv.w;
    }
    // kp for this wave's m-tiles, both 16-row groups of the 32-chunk
    s16x8 ah[2][2], al[2][2];
    float dg[2][4];
#pragma unroll
    for (int g = 0; g < 2; g++) {
      float ss = 0.f;
      const float* kb = K + ((size_t)(bh * NN + n0 + g * 16 + l15)) * DD + quad * 8;
#pragma unroll
      for (int s = 0; s < 2; s++) split8(kb + s * 32, ah[g][s], al[g][s], ss);
      ss += __shfl_xor(ss, 16);
      ss += __shfl_xor(ss, 32);
#pragma unroll
      for (int r = 0; r < 4; r++) dg[g][r] = HDN2 * __shfl(ss, quad * 4 + r);
    }
#pragma unroll 5
    for (int ti = 0; ti < 5; ti++) {
      const int t = wave + ti * 4;
      if (t < 17) {
#pragma unroll
        for (int g = 0; g < 2; g++) {
          f32x4 dd = zero4;
#pragma unroll
          for (int s = 0; s < 2; s++) {
            s16x8 b8h = *(const s16x8*)(pbh + (t * 16 + l15) * DD + s * 32 + quad * 8);
            s16x8 b8l = *(const s16x8*)(pbl + (t * 16 + l15) * DD + s * 32 + quad * 8);
            MFMA(dd, ah[g][s], b8h); MFMA(dd, al[g][s], b8h); MFMA(dd, ah[g][s], b8l);
          }
          float4 kp;
          float* kpp = (float*)&kp;
#pragma unroll
          for (int r = 0; r < 4; r++)
            kpp[r] = RATIO * (__expf(DN * dd[r] - dg[g][r] - stab) + EPSF);
          if (t == 16 && l15 >= 10) { kp.x = kp.y = kp.z = kp.w = 0.f; }  // padded m
          kcp[ti] += kpp[0] + kpp[1] + kpp[2] + kpp[3];
          *(float4*)(kpb + (t * 16 + l15) * 36 + g * 16 + quad * 4) = kp;
        }
      }
    }
    __syncthreads();
    // ctx GEMM: acc[m-tile][d-tile] += kp^T . v (bf16x3)
    s16x8 vbh[4], vbl[4];
#pragma unroll
    for (int dt = 0; dt < 4; dt++) {
      float dummy = 0.f;
      split8(vT + (dt * 16 + l15) * 36 + quad * 8, vbh[dt], vbl[dt], dummy);
    }
#pragma unroll 5
    for (int ti = 0; ti < 5; ti++) {
      const int t = wave + ti * 4;
      if (t < 17) {
        s16x8 kah, kal; float dummy = 0.f;
        split8(kpb + (t * 16 + l15) * 36 + quad * 8, kah, kal, dummy);
#pragma unroll
        for (int dt = 0; dt < 4; dt++) {
          MFMA(acc[ti][dt], kah, vbh[dt]);
          MFMA(acc[ti][dt], kal, vbh[dt]);
          MFMA(acc[ti][dt], kah, vbl[dt]);
        }
      }
    }
    __syncthreads();
  }
  // epilogue: kc + ctx atomics (32-way contention per address)
#pragma unroll 5
  for (int ti = 0; ti < 5; ti++) {
    const int t = wave + ti * 4;
    if (t < 17) {
      float kc = kcp[ti];
      kc += __shfl_xor(kc, 16);
      kc += __shfl_xor(kc, 32);
      if (lane < 16) atomicAdd(&ws[WS_KC + bh * CTS + t * 16 + lane], kc);
#pragma unroll
      for (int dt = 0; dt < 4; dt++)
#pragma unroll
        for (int r = 0; r < 4; r++) {
          int m = t * 16 + quad * 4 + r;
          atomicAdd(&ws[WS_CTX + ((size_t)(bh * MP + m)) * DD + dt * 16 + l15],
                    acc[ti][dt][r]);
        }
    }
  }
}

// ---------------- ctxT: ctx fp32 [m][d] -> bf16 hi/lo transposed [d][288] ----------------
__global__ __launch_bounds__(256) void ctxt_kernel(
    const float* __restrict__ ws, unsigned short* __restrict__ cth,
    unsigned short* __restrict__ ctl) {
  const int bh = blockIdx.x;
  const int idx = blockIdx.y * 256 + threadIdx.x;   // < 64*288
  const int d = idx / CTS, m = idx % CTS;
  float f = (m < MP) ? ws[WS_CTX + ((size_t)(bh * MP + m)) * DD + d] : 0.f;
  unsigned short h = f2bf(f);
  cth[((size_t)(bh * DD) + d) * CTS + m] = h;
  ctl[((size_t)(bh * DD) + d) * CTS + m] = f2bf(f - bf2f(h));
}

// ---------------- out: qp = f(q.projT) with per-row max; out = qp.ctx * dinv ----------------
__global__ __launch_bounds__(256) void out_kernel(
    const float* __restrict__ Q, const unsigned short* __restrict__ pbh,
    const unsigned short* __restrict__ pbl, const unsigned short* __restrict__ cth,
    const unsigned short* __restrict__ ctl, const float* __restrict__ ws,
    float* __restrict__ Out) {
  __shared__ float qpb[4][16 * 36];   // per-wave C->A bounce, pad 36
  const int tid = threadIdx.x;
  const int wave = tid >> 6, lane = tid & 63;
  const int l15 = lane & 15, quad = lane >> 4;
  const int bh = blockIdx.x;
  const int n0 = blockIdx.y * 64 + wave * 16;
  f32x4 zero4 = {0.f, 0.f, 0.f, 0.f};
  s16x8 ah[2], al[2];
  float ss = 0.f;
  const float* qb = Q + ((size_t)(bh * NN + n0 + l15)) * DD + quad * 8;
#pragma unroll
  for (int s = 0; s < 2; s++) split8(qb + s * 32, ah[s], al[s], ss);
  ss += __shfl_xor(ss, 16);
  ss += __shfl_xor(ss, 32);
  float dg[4];
#pragma unroll
  for (int r = 0; r < 4; r++) dg[r] = HDN2 * __shfl(ss, quad * 4 + r);
  // pass 1: per-row max of raw q.projT
  float mx[4] = {-1e30f, -1e30f, -1e30f, -1e30f};
  for (int t = 0; t < 17; t++) {
    f32x4 dd = zero4;
#pragma unroll
    for (int s = 0; s < 2; s++) {
      s16x8 b8h = *(const s16x8*)(pbh + (t * 16 + l15) * DD + s * 32 + quad * 8);
      s16x8 b8l = *(const s16x8*)(pbl + (t * 16 + l15) * DD + s * 32 + quad * 8);
      MFMA(dd, ah[s], b8h); MFMA(dd, al[s], b8h); MFMA(dd, ah[s], b8l);
    }
    if (!(t == 16 && l15 >= 10)) {
#pragma unroll
      for (int r = 0; r < 4; r++) mx[r] = fmaxf(mx[r], dd[r]);
    }
  }
  float sub[4];
#pragma unroll
  for (int r = 0; r < 4; r++) {
#pragma unroll
    for (int d = 1; d < 16; d <<= 1) mx[r] = fmaxf(mx[r], __shfl_xor(mx[r], d));
    sub[r] = dg[r] + DN * mx[r];
  }
  // pass 2: recompute dd 32-m at a time, exp -> qp, bounce, GEMM vs ctxT
  f32x4 oa[4];
#pragma unroll
  for (int dt = 0; dt < 4; dt++) oa[dt] = zero4;
  float dn[4] = {0.f, 0.f, 0.f, 0.f};
  float* myqpb = qpb[wave];
  for (int s9 = 0; s9 < 9; s9++) {
#pragma unroll
    for (int u = 0; u < 2; u++) {
      const int t = s9 * 2 + u;
      if (t < 17) {
        f32x4 dd = zero4;
#pragma unroll
        for (int s = 0; s < 2; s++) {
          s16x8 b8h = *(const s16x8*)(pbh + (t * 16 + l15) * DD + s * 32 + quad * 8);
          s16x8 b8l = *(const s16x8*)(pbl + (t * 16 + l15) * DD + s * 32 + quad * 8);
          MFMA(dd, ah[s], b8h); MFMA(dd, al[s], b8h); MFMA(dd, ah[s], b8l);
        }
        const float kcv = ws[WS_KC + bh * CTS + t * 16 + l15];
#pragma unroll
        for (int r = 0; r < 4; r++) {
          float qp = RATIO * (__expf(DN * dd[r] - sub[r]) + EPSF);
          if (t == 16 && l15 >= 10) qp = 0.f;
          dn[r] += qp * kcv;
          myqpb[(quad * 4 + r) * 36 + u * 16 + l15] = qp;
        }
      } else {   // t == 17: zero pad columns
#pragma unroll
        for (int r = 0; r < 4; r++) myqpb[(quad * 4 + r) * 36 + 16 + l15] = 0.f;
      }
    }
    s16x8 qah, qal; float dummy = 0.f;
    split8(myqpb + l15 * 36 + quad * 8, qah, qal, dummy);   // wave-private: no barrier
#pragma unroll
    for (int dt = 0; dt < 4; dt++) {
      const unsigned short* cb = cth + ((size_t)(bh * DD + dt * 16 + l15)) * CTS + s9 * 32 + quad * 8;
      const unsigned short* cl = ctl + ((size_t)(bh * DD + dt * 16 + l15)) * CTS + s9 * 32 + quad * 8;
      s16x8 c8h = *(const s16x8*)cb;
      s16x8 c8l = *(const s16x8*)cl;
      MFMA(oa[dt], qah, c8h);
      MFMA(oa[dt], qal, c8h);
      MFMA(oa[dt], qah, c8l);
    }
  }
#pragma unroll
  for (int r = 0; r < 4; r++) {
#pragma unroll
    for (int d = 1; d < 16; d <<= 1) dn[r] += __shfl_xor(dn[r], d);
    dn[r] = 1.0f / dn[r];
  }
#pragma unroll
  for (int dt = 0; dt < 4; dt++)
#pragma unroll
    for (int r = 0; r < 4; r++)
      Out[((size_t)(bh * NN + n0 + quad * 4 + r)) * DD + dt * 16 + l15] = oa[dt][r] * dn[r];
}

extern "C" void kernel_launch(void* const* d_in, const int* in_sizes, int n_in,
                              void* d_out, int out_size, void* d_ws, size_t ws_size,
                              hipStream_t stream) {
  const float* q = (const float*)d_in[0];
  const float* k = (const float*)d_in[1];
  const float* v = (const float*)d_in[2];
  const float* p = (const float*)d_in[3];
  float* out = (float*)d_out;
  float* ws  = (float*)d_ws;
  unsigned short* pbh = (unsigned short*)(ws + WS_PBH);
  unsigned short* pbl = pbh + MP * DD;
  unsigned short* cth = (unsigned short*)(ws + WS_PBH + (2 * MP * DD) / 2);
  unsigned short* ctl = cth + (size_t)BHN * DD * CTS;

  hipMemsetAsync(ws + ZERO_OFF, 0, ZERO_CNT * sizeof(float), stream);
  prep_kernel<<<68, 256, 0, stream>>>(p, pbh, pbl);
  kmax_kernel<<<dim3(BHN, 256), 256, 0, stream>>>(k, pbh, pbl, ws);
  stab_kernel<<<BHN, 256, 0, stream>>>(ws);
  ctx_kernel<<<dim3(BHN, 32), 256, 0, stream>>>(k, v, pbh, pbl, ws);
  ctxt_kernel<<<dim3(BHN, 72), 256, 0, stream>>>(ws, cth, ctl);
  out_kernel<<<dim3(BHN, 256), 256, 0, stream>>>(q, pbh, pbl, cth, ctl, ws, out);
}

// Round 3
// 539.580 us; speedup vs baseline: 3.4351x; 1.3978x over previous
//
#include <hip/hip_runtime.h>
#include <hip/hip_bf16.h>
#include <math.h>

// Problem constants: B*H=16, N=16384, D=64, M=266 (padded to 272 = 17 tiles of 16)
#define BHN 16
#define NN 16384
#define DD 64
#define MM 266
#define MP 272          // padded M (17 MFMA tiles)
#define CTS 288         // ctxT / kc row stride

constexpr float DN    = 0.35355339059327373f;   // 64^-0.25
constexpr float HDN2  = 0.0625f;                // 0.5 * DN^2
constexpr float RATIO = 0.0613139339f;          // 266^-0.5
constexpr float EPSF  = 1e-4f;

// ws layout (float offsets)
#define WS_STAB 0                         // [16]
#define WS_PART 16                        // [16][64]
#define WS_KC   1040                      // [16][288] final kc
#define WS_KCS  5648                      // [4][16][288] slices
#define WS_CTXS 24080                     // [4][16][272][64] slices
#define CTX_SLICE (BHN * MP * DD)         // 278528
#define KC_SLICE  (BHN * CTS)             // 4608
#define WS_PBH  1138192                   // pbh ushort[17408] (=8704 floats), pbl follows
#define WS_CTH  1155600                   // cth ushort[16*64*288], ctl follows
#define ZERO_OFF 5648
#define ZERO_CNT 1132544                  // KCS + CTXS

typedef __attribute__((ext_vector_type(8))) short s16x8;   // 8 bf16 (4 VGPRs)
typedef __attribute__((ext_vector_type(4))) float f32x4;

#define MFMA(acc, a, b) acc = __builtin_amdgcn_mfma_f32_16x16x32_bf16(a, b, acc, 0, 0, 0)

__device__ __forceinline__ float bf2f_u(unsigned short h) {
  union { unsigned u; float f; } v; v.u = ((unsigned)h) << 16; return v.f;
}
// pack 2 floats -> 2 bf16 (RNE) via v_cvt_pk_bf16_f32; low16 = a, high16 = b
__device__ __forceinline__ unsigned pk_bf16(float a, float b) {
  float2 f; f.x = a; f.y = b;
  __hip_bfloat162 h = __float22bfloat162_rn(f);
  union { __hip_bfloat162 h; unsigned u; } c; c.h = h;
  return c.u;
}
// 8 floats -> bf16 hi + lo fragments
__device__ __forceinline__ void split8(const float* v, s16x8& hi, s16x8& lo) {
  union U { s16x8 s; unsigned u[4]; } H, L;
#pragma unroll
  for (int i = 0; i < 4; i++) {
    float a = v[2 * i], b = v[2 * i + 1];
    unsigned uh = pk_bf16(a, b);
    H.u[i] = uh;
    float r0 = a - bf2f_u((unsigned short)(uh & 0xffffu));
    float r1 = b - bf2f_u((unsigned short)(uh >> 16));
    L.u[i] = pk_bf16(r0, r1);
  }
  hi = H.s; lo = L.s;
}
__device__ __forceinline__ void split8g(const float* __restrict__ p,
                                        s16x8& hi, s16x8& lo, float& ss) {
  float4 f0 = *(const float4*)p;
  float4 f1 = *(const float4*)(p + 4);
  float v[8] = {f0.x, f0.y, f0.z, f0.w, f1.x, f1.y, f1.z, f1.w};
#pragma unroll
  for (int i = 0; i < 8; i++) ss += v[i] * v[i];
  split8(v, hi, lo);
}
__device__ __forceinline__ void split8l(const float* p, s16x8& hi, s16x8& lo) {
  float4 f0 = *(const float4*)p;
  float4 f1 = *(const float4*)(p + 4);
  float v[8] = {f0.x, f0.y, f0.z, f0.w, f1.x, f1.y, f1.z, f1.w};
  split8(v, hi, lo);
}

// ---------------- prep: proj -> bf16 hi/lo [272][64], pads zero ----------------
__global__ void prep_kernel(const float* __restrict__ P,
                            unsigned short* __restrict__ pbh,
                            unsigned short* __restrict__ pbl) {
  int idx = blockIdx.x * 256 + threadIdx.x;
  if (idx < MP * DD) {
    float f = (idx < MM * DD) ? P[idx] : 0.f;
    unsigned short h = (unsigned short)(pk_bf16(f, 0.f) & 0xffffu);
    pbh[idx] = h;
    pbl[idx] = (unsigned short)(pk_bf16(f - bf2f_u(h), 0.f) & 0xffffu);
  }
}

// ---------------- kmax: per-block max of raw k.projT (64 rows/wave) ----------------
__global__ __launch_bounds__(256) void kmax_kernel(
    const float* __restrict__ K, const unsigned short* __restrict__ pbh,
    const unsigned short* __restrict__ pbl, float* __restrict__ ws) {
  const int tid = threadIdx.x;
  const int wave = tid >> 6, lane = tid & 63;
  const int l15 = lane & 15, quad = lane >> 4;
  const int bh = blockIdx.x;
  const int n0 = blockIdx.y * 256 + wave * 64;
  s16x8 ah[4][2], al[4][2];
  float ssd = 0.f;
#pragma unroll
  for (int g = 0; g < 4; g++)
#pragma unroll
    for (int s = 0; s < 2; s++)
      split8g(K + ((size_t)(bh * NN + n0 + g * 16 + l15)) * DD + s * 32 + quad * 8,
              ah[g][s], al[g][s], ssd);
  float mx = -1e30f;
  for (int t = 0; t < 17; t++) {
    f32x4 dd[4] = {{0,0,0,0},{0,0,0,0},{0,0,0,0},{0,0,0,0}};
#pragma unroll
    for (int s = 0; s < 2; s++) {
      s16x8 b8h = *(const s16x8*)(pbh + (t * 16 + l15) * DD + s * 32 + quad * 8);
      s16x8 b8l = *(const s16x8*)(pbl + (t * 16 + l15) * DD + s * 32 + quad * 8);
#pragma unroll
      for (int g = 0; g < 4; g++) {
        MFMA(dd[g], ah[g][s], b8h); MFMA(dd[g], al[g][s], b8h); MFMA(dd[g], ah[g][s], b8l);
      }
    }
    if (!(t == 16 && l15 >= 10)) {
#pragma unroll
      for (int g = 0; g < 4; g++)
        mx = fmaxf(mx, fmaxf(fmaxf(dd[g][0], dd[g][1]), fmaxf(dd[g][2], dd[g][3])));
    }
  }
#pragma unroll
  for (int d = 1; d < 64; d <<= 1) mx = fmaxf(mx, __shfl_xor(mx, d));
  __shared__ float red[4];
  if (lane == 0) red[wave] = mx;
  __syncthreads();
  if (tid == 0)
    ws[WS_PART + bh * 64 + blockIdx.y] = fmaxf(fmaxf(red[0], red[1]), fmaxf(red[2], red[3]));
}

// ---------------- stab: reduce 64 partials ----------------
__global__ void stab_kernel(float* __restrict__ ws) {
  const int bh = blockIdx.x, lane = threadIdx.x;
  float m = ws[WS_PART + bh * 64 + lane];
#pragma unroll
  for (int d = 1; d < 64; d <<= 1) m = fmaxf(m, __shfl_xor(m, d));
  if (lane == 0) ws[WS_STAB + bh] = DN * m;
}

// ---------------- ctx: kp = f(k.projT); ctx += kp^T.v; kc += sum kp ----------------
__global__ __launch_bounds__(256) void ctx_kernel(
    const float* __restrict__ K, const float* __restrict__ V,
    const unsigned short* __restrict__ pbh, const unsigned short* __restrict__ pbl,
    float* __restrict__ ws) {
  __shared__ float vT[64 * 36];      // v chunk transposed [d][n]
  __shared__ float kpb[MP * 36];     // kp chunk transposed-ish [m-row][n]
  const int tid = threadIdx.x;
  const int wave = tid >> 6, lane = tid & 63;
  const int l15 = lane & 15, quad = lane >> 4;
  const int bh = blockIdx.x;
  const int slice = blockIdx.y & 3;
  float* ctxs = ws + WS_CTXS + (size_t)slice * CTX_SLICE;
  float* kcs  = ws + WS_KCS + slice * KC_SLICE;
  const float stab = ws[WS_STAB + bh];
  f32x4 zero4 = {0.f, 0.f, 0.f, 0.f};
  f32x4 acc[5][4];
#pragma unroll
  for (int i = 0; i < 5; i++)
#pragma unroll
    for (int j = 0; j < 4; j++) acc[i][j] = zero4;
  float kcp[5] = {0.f, 0.f, 0.f, 0.f, 0.f};

  for (int it = 0; it < 16; it++) {
    const int n0 = blockIdx.y * 512 + it * 32;
    // stage vT: conflict-free transposed write (n varies across lanes, d uniform)
#pragma unroll
    for (int j = 0; j < 2; j++) {
      const int n = tid & 31;
      const int d4 = ((tid >> 5) + j * 8) * 4;
      float4 vv = *(const float4*)(V + ((size_t)(bh * NN + n0 + n)) * DD + d4);
      vT[(d4 + 0) * 36 + n] = vv.x;
      vT[(d4 + 1) * 36 + n] = vv.y;
      vT[(d4 + 2) * 36 + n] = vv.z;
      vT[(d4 + 3) * 36 + n] = vv.w;
    }
    // kp for this wave's m-tiles over both 16-row groups
    s16x8 ah[2][2], al[2][2];
    float dg[2][4];
#pragma unroll
    for (int g = 0; g < 2; g++) {
      float ss = 0.f;
#pragma unroll
      for (int s = 0; s < 2; s++)
        split8g(K + ((size_t)(bh * NN + n0 + g * 16 + l15)) * DD + s * 32 + quad * 8,
                ah[g][s], al[g][s], ss);
      ss += __shfl_xor(ss, 16);
      ss += __shfl_xor(ss, 32);
#pragma unroll
      for (int r = 0; r < 4; r++) dg[g][r] = HDN2 * __shfl(ss, quad * 4 + r);
    }
#pragma unroll 5
    for (int ti = 0; ti < 5; ti++) {
      const int t = wave + ti * 4;
      if (t < 17) {
        f32x4 dd[2] = {zero4, zero4};
#pragma unroll
        for (int s = 0; s < 2; s++) {
          s16x8 b8h = *(const s16x8*)(pbh + (t * 16 + l15) * DD + s * 32 + quad * 8);
          s16x8 b8l = *(const s16x8*)(pbl + (t * 16 + l15) * DD + s * 32 + quad * 8);
#pragma unroll
          for (int g = 0; g < 2; g++) {
            MFMA(dd[g], ah[g][s], b8h); MFMA(dd[g], al[g][s], b8h); MFMA(dd[g], ah[g][s], b8l);
          }
        }
#pragma unroll
        for (int g = 0; g < 2; g++) {
          float4 kp;
          float* kpp = (float*)&kp;
#pragma unroll
          for (int r = 0; r < 4; r++)
            kpp[r] = RATIO * (__expf(DN * dd[g][r] - dg[g][r] - stab) + EPSF);
          if (t == 16 && l15 >= 10) { kp.x = kp.y = kp.z = kp.w = 0.f; }
          kcp[ti] += kpp[0] + kpp[1] + kpp[2] + kpp[3];
          *(float4*)(kpb + (t * 16 + l15) * 36 + g * 16 + quad * 4) = kp;
        }
      }
    }
    __syncthreads();   // tile data ready
    s16x8 vbh[4], vbl[4];
#pragma unroll
    for (int dt = 0; dt < 4; dt++)
      split8l(vT + (dt * 16 + l15) * 36 + quad * 8, vbh[dt], vbl[dt]);
#pragma unroll 5
    for (int ti = 0; ti < 5; ti++) {
      const int t = wave + ti * 4;
      if (t < 17) {
        s16x8 kah, kal;
        split8l(kpb + (t * 16 + l15) * 36 + quad * 8, kah, kal);
#pragma unroll
        for (int dt = 0; dt < 4; dt++) {
          MFMA(acc[ti][dt], kah, vbh[dt]);
          MFMA(acc[ti][dt], kal, vbh[dt]);
          MFMA(acc[ti][dt], kah, vbl[dt]);
        }
      }
    }
    __syncthreads();   // readers done before next chunk overwrites
  }
  // epilogue: slice atomics (8-way contention)
#pragma unroll 5
  for (int ti = 0; ti < 5; ti++) {
    const int t = wave + ti * 4;
    if (t < 17) {
      float kc = kcp[ti];
      kc += __shfl_xor(kc, 16);
      kc += __shfl_xor(kc, 32);
      if (lane < 16) atomicAdd(&kcs[bh * CTS + t * 16 + lane], kc);
#pragma unroll
      for (int dt = 0; dt < 4; dt++)
#pragma unroll
        for (int r = 0; r < 4; r++) {
          int m = t * 16 + quad * 4 + r;
          atomicAdd(&ctxs[((size_t)(bh * MP + m)) * DD + dt * 16 + l15], acc[ti][dt][r]);
        }
    }
  }
}

// ---------------- ctxt: reduce slices; ctx -> bf16 hi/lo transposed; kc final ----------------
__global__ __launch_bounds__(256) void ctxt_kernel(
    float* __restrict__ ws, unsigned short* __restrict__ cth,
    unsigned short* __restrict__ ctl) {
  const int bh = blockIdx.x;
  const int idx = blockIdx.y * 256 + threadIdx.x;   // < 64*288
  const int d = idx / CTS, m = idx % CTS;
  float f = 0.f;
  if (m < MP) {
#pragma unroll
    for (int s = 0; s < 4; s++)
      f += ws[WS_CTXS + (size_t)s * CTX_SLICE + ((size_t)(bh * MP + m)) * DD + d];
  }
  unsigned short h = (unsigned short)(pk_bf16(f, 0.f) & 0xffffu);
  cth[((size_t)(bh * DD) + d) * CTS + m] = h;
  ctl[((size_t)(bh * DD) + d) * CTS + m] =
      (unsigned short)(pk_bf16(f - bf2f_u(h), 0.f) & 0xffffu);
  if (d == 0) {
    float kc = 0.f;
#pragma unroll
    for (int s = 0; s < 4; s++) kc += ws[WS_KCS + s * KC_SLICE + bh * CTS + m];
    ws[WS_KC + bh * CTS + m] = kc;
  }
}

// ---------------- out: qp (2-pass row max) -> out = qp.ctx * dinv (32 rows/wave) ----------------
__global__ __launch_bounds__(256) void out_kernel(
    const float* __restrict__ Q, const unsigned short* __restrict__ pbh,
    const unsigned short* __restrict__ pbl, const unsigned short* __restrict__ cth,
    const unsigned short* __restrict__ ctl, const float* __restrict__ ws,
    float* __restrict__ Out) {
  __shared__ float qpb[4][2][16 * 36];   // per-wave, per-group bounce (18.4 KB)
  const int tid = threadIdx.x;
  const int wave = tid >> 6, lane = tid & 63;
  const int l15 = lane & 15, quad = lane >> 4;
  const int bh = blockIdx.x;
  const int n0 = blockIdx.y * 128 + wave * 32;
  f32x4 zero4 = {0.f, 0.f, 0.f, 0.f};
  s16x8 ah[2][2], al[2][2];
  float sub[2][4];
#pragma unroll
  for (int g = 0; g < 2; g++) {
    float ss = 0.f;
#pragma unroll
    for (int s = 0; s < 2; s++)
      split8g(Q + ((size_t)(bh * NN + n0 + g * 16 + l15)) * DD + s * 32 + quad * 8,
              ah[g][s], al[g][s], ss);
    ss += __shfl_xor(ss, 16);
    ss += __shfl_xor(ss, 32);
#pragma unroll
    for (int r = 0; r < 4; r++) sub[g][r] = HDN2 * __shfl(ss, quad * 4 + r);
  }
  // pass 1: per-row max of raw q.projT
  float mx[2][4];
#pragma unroll
  for (int g = 0; g < 2; g++)
#pragma unroll
    for (int r = 0; r < 4; r++) mx[g][r] = -1e30f;
  for (int t = 0; t < 17; t++) {
    f32x4 dd[2] = {zero4, zero4};
#pragma unroll
    for (int s = 0; s < 2; s++) {
      s16x8 b8h = *(const s16x8*)(pbh + (t * 16 + l15) * DD + s * 32 + quad * 8);
      s16x8 b8l = *(const s16x8*)(pbl + (t * 16 + l15) * DD + s * 32 + quad * 8);
#pragma unroll
      for (int g = 0; g < 2; g++) {
        MFMA(dd[g], ah[g][s], b8h); MFMA(dd[g], al[g][s], b8h); MFMA(dd[g], ah[g][s], b8l);
      }
    }
    if (!(t == 16 && l15 >= 10)) {
#pragma unroll
      for (int g = 0; g < 2; g++)
#pragma unroll
        for (int r = 0; r < 4; r++) mx[g][r] = fmaxf(mx[g][r], dd[g][r]);
    }
  }
#pragma unroll
  for (int g = 0; g < 2; g++)
#pragma unroll
    for (int r = 0; r < 4; r++) {
#pragma unroll
      for (int d = 1; d < 16; d <<= 1) mx[g][r] = fmaxf(mx[g][r], __shfl_xor(mx[g][r], d));
      sub[g][r] += DN * mx[g][r];   // diag + stab
    }
  // pass 2
  f32x4 oa[2][4];
#pragma unroll
  for (int g = 0; g < 2; g++)
#pragma unroll
    for (int dt = 0; dt < 4; dt++) oa[g][dt] = zero4;
  float dn[2][4] = {{0.f,0.f,0.f,0.f},{0.f,0.f,0.f,0.f}};
  for (int s9 = 0; s9 < 9; s9++) {
#pragma unroll
    for (int u = 0; u < 2; u++) {
      const int t = s9 * 2 + u;
      if (t < 17) {
        f32x4 dd[2] = {zero4, zero4};
#pragma unroll
        for (int s = 0; s < 2; s++) {
          s16x8 b8h = *(const s16x8*)(pbh + (t * 16 + l15) * DD + s * 32 + quad * 8);
          s16x8 b8l = *(const s16x8*)(pbl + (t * 16 + l15) * DD + s * 32 + quad * 8);
#pragma unroll
          for (int g = 0; g < 2; g++) {
            MFMA(dd[g], ah[g][s], b8h); MFMA(dd[g], al[g][s], b8h); MFMA(dd[g], ah[g][s], b8l);
          }
        }
        const float kcv = ws[WS_KC + bh * CTS + t * 16 + l15];
#pragma unroll
        for (int g = 0; g < 2; g++)
#pragma unroll
          for (int r = 0; r < 4; r++) {
            float qp = RATIO * (__expf(DN * dd[g][r] - sub[g][r]) + EPSF);
            if (t == 16 && l15 >= 10) qp = 0.f;
            dn[g][r] += qp * kcv;
            qpb[wave][g][(quad * 4 + r) * 36 + u * 16 + l15] = qp;
          }
      } else {
#pragma unroll
        for (int g = 0; g < 2; g++)
#pragma unroll
          for (int r = 0; r < 4; r++) qpb[wave][g][(quad * 4 + r) * 36 + 16 + l15] = 0.f;
      }
    }
    s16x8 qah[2], qal[2];
#pragma unroll
    for (int g = 0; g < 2; g++)
      split8l(qpb[wave][g] + l15 * 36 + quad * 8, qah[g], qal[g]);  // wave-private: no barrier
#pragma unroll
    for (int dt = 0; dt < 4; dt++) {
      s16x8 c8h = *(const s16x8*)(cth + ((size_t)(bh * DD + dt * 16 + l15)) * CTS + s9 * 32 + quad * 8);
      s16x8 c8l = *(const s16x8*)(ctl + ((size_t)(bh * DD + dt * 16 + l15)) * CTS + s9 * 32 + quad * 8);
#pragma unroll
      for (int g = 0; g < 2; g++) {
        MFMA(oa[g][dt], qah[g], c8h);
        MFMA(oa[g][dt], qal[g], c8h);
        MFMA(oa[g][dt], qah[g], c8l);
      }
    }
  }
#pragma unroll
  for (int g = 0; g < 2; g++)
#pragma unroll
    for (int r = 0; r < 4; r++) {
#pragma unroll
      for (int d = 1; d < 16; d <<= 1) dn[g][r] += __shfl_xor(dn[g][r], d);
      dn[g][r] = 1.0f / dn[g][r];
    }
#pragma unroll
  for (int g = 0; g < 2; g++)
#pragma unroll
    for (int dt = 0; dt < 4; dt++)
#pragma unroll
      for (int r = 0; r < 4; r++)
        Out[((size_t)(bh * NN + n0 + g * 16 + quad * 4 + r)) * DD + dt * 16 + l15] =
            oa[g][dt][r] * dn[g][r];
}

extern "C" void kernel_launch(void* const* d_in, const int* in_sizes, int n_in,
                              void* d_out, int out_size, void* d_ws, size_t ws_size,
                              hipStream_t stream) {
  const float* q = (const float*)d_in[0];
  const float* k = (const float*)d_in[1];
  const float* v = (const float*)d_in[2];
  const float* p = (const float*)d_in[3];
  float* out = (float*)d_out;
  float* ws  = (float*)d_ws;
  unsigned short* pbh = (unsigned short*)(ws + WS_PBH);
  unsigned short* pbl = pbh + MP * DD;
  unsigned short* cth = (unsigned short*)(ws + WS_CTH);
  unsigned short* ctl = cth + (size_t)BHN * DD * CTS;

  hipMemsetAsync(ws + ZERO_OFF, 0, (size_t)ZERO_CNT * sizeof(float), stream);
  prep_kernel<<<68, 256, 0, stream>>>(p, pbh, pbl);
  kmax_kernel<<<dim3(BHN, 64), 256, 0, stream>>>(k, pbh, pbl, ws);
  stab_kernel<<<BHN, 64, 0, stream>>>(ws);
  ctx_kernel<<<dim3(BHN, 32), 256, 0, stream>>>(k, v, pbh, pbl, ws);
  ctxt_kernel<<<dim3(BHN, 72), 256, 0, stream>>>(ws, cth, ctl);
  out_kernel<<<dim3(BHN, 128), 256, 0, stream>>>(q, pbh, pbl, cth, ctl, ws, out);
}